// Round 6
// baseline (224.616 us; speedup 1.0000x reference)
//
#include <hip/hip_runtime.h>
#include <hip/hip_fp16.h>

#define NN   100000
#define E0   1600000
#define ET   1700000
#define NEG  0.2f
#define EPSV 1e-16f
#define NBK  1563           // dst buckets of 64 node ids (ceil(NN/64))
#define CAP  1536           // LDS edge-list capacity (bucket mean 1088, sigma 33)
#define BS   1024
#define NBLK4 ((ET + 4 * BS - 1) / (4 * BS))   // 416 (single-pass bscat)
#define GEMM_NB 782         // ceil(NN/32/4) tiles of 4 waves
#define BC_NB   416         // bcount blocks in merged kernel (256 thr, 16 e/thr)
#define E1_NB   6256        // 782 rounds x 8 XCD lanes (head = lane>>1, 2 buckets/round)

typedef _Float16 half8 __attribute__((ext_vector_type(8)));
typedef float f32x16 __attribute__((ext_vector_type(16)));

// ---- MERGED: blocks [0,782) = MFMA GEMM; blocks [782,1198) = bucket count.
// h1h stored head-major quad [h][n][16] (XCD slicing); asr/adr stored
// node-major [n][4] (16B rows for bsort's coalesced per-edge gather). ----
__global__ __launch_bounds__(256) void k_g1bc(
    const float* __restrict__ x, const int* __restrict__ ei,
    const float* __restrict__ W1, const float* __restrict__ as1,
    const float* __restrict__ ad1,
    __half* __restrict__ h1h, float* __restrict__ asr, float* __restrict__ adr,
    int* __restrict__ bcnt)
{
    int t = threadIdx.x;
    if (blockIdx.x >= GEMM_NB) {
        __shared__ int cnt[NBK];
        for (int i = t; i < NBK; i += 256) cnt[i] = 0;
        __syncthreads();
        int base = (blockIdx.x - GEMM_NB) * (256 * 16);
#pragma unroll
        for (int k = 0; k < 16; ++k) {
            int idx = base + k * 256 + t;
            if (idx < ET) {
                int d = (idx < E0) ? ei[E0 + idx] : (idx - E0);
                atomicAdd(&cnt[d >> 6], 1);
            }
        }
        __syncthreads();
        for (int i = t; i < NBK; i += 256) if (cnt[i]) atomicAdd(&bcnt[i], cnt[i]);
        return;
    }
    // ---------------- GEMM body (R14 math, verified) ----------------
    __shared__ float Wl[4096];
    __shared__ float Ul[512];
    for (int i = t; i < 4096; i += 256) Wl[i] = W1[i];
    __syncthreads();
    if (t < 64) {
        int k = t;
#pragma unroll
        for (int h = 0; h < 4; ++h) {
            float su = 0.f, du = 0.f;
#pragma unroll
            for (int c = 0; c < 16; ++c) {
                float w = Wl[k * 64 + h * 16 + c];
                su += w * as1[h * 16 + c];
                du += w * ad1[h * 16 + c];
            }
            Ul[k * 8 + h] = su;
            Ul[k * 8 + 4 + h] = du;
        }
    }
    __syncthreads();
    int lane = t & 63, wv = t >> 6;
    int col = lane & 31, q = lane >> 5;
    half8 bf0[4], bf1[4], bf2[4];
#pragma unroll
    for (int kc = 0; kc < 4; ++kc) {
#pragma unroll
        for (int j = 0; j < 8; ++j) {
            int k = kc * 16 + q * 8 + j;
            bf0[kc][j] = (_Float16)Wl[k * 64 + col];
            bf1[kc][j] = (_Float16)Wl[k * 64 + 32 + col];
            bf2[kc][j] = (col < 8) ? (_Float16)Ul[k * 8 + col] : (_Float16)0.f;
        }
    }
    int tile = blockIdx.x * 4 + wv;
    int n0 = tile * 32;
    if (n0 >= NN) return;
    half8 af[4];
    const float* xrow = x + (size_t)(n0 + col) * 64;
#pragma unroll
    for (int kc = 0; kc < 4; ++kc) {
        float4 xa = *(const float4*)(xrow + kc * 16 + q * 8);
        float4 xb = *(const float4*)(xrow + kc * 16 + q * 8 + 4);
        af[kc][0] = (_Float16)xa.x; af[kc][1] = (_Float16)xa.y;
        af[kc][2] = (_Float16)xa.z; af[kc][3] = (_Float16)xa.w;
        af[kc][4] = (_Float16)xb.x; af[kc][5] = (_Float16)xb.y;
        af[kc][6] = (_Float16)xb.z; af[kc][7] = (_Float16)xb.w;
    }
    f32x16 c0 = {}, c1 = {}, c2 = {};
#pragma unroll
    for (int kc = 0; kc < 4; ++kc) {
        c0 = __builtin_amdgcn_mfma_f32_32x32x16_f16(af[kc], bf0[kc], c0, 0, 0, 0);
        c1 = __builtin_amdgcn_mfma_f32_32x32x16_f16(af[kc], bf1[kc], c1, 0, 0, 0);
        c2 = __builtin_amdgcn_mfma_f32_32x32x16_f16(af[kc], bf2[kc], c2, 0, 0, 0);
    }
    // head-major h1h: c0 -> heads {0,1}, c1 -> heads {2,3}; rows of 16 halves (32B)
    int hA = col >> 4, cc = col & 15;
#pragma unroll
    for (int reg = 0; reg < 16; ++reg) {
        int row = (reg & 3) + 8 * (reg >> 2) + 4 * q;
        size_t n = (size_t)(n0 + row);
        h1h[((size_t)hA * NN + n) * 16 + cc]       = __float2half(c0[reg]);
        h1h[((size_t)(hA + 2) * NN + n) * 16 + cc] = __float2half(c1[reg]);
    }
    if (col < 8) {
        float* dst = (col < 4) ? asr : adr;
        int h = col & 3;
#pragma unroll
        for (int reg = 0; reg < 16; ++reg) {
            int row = (reg & 3) + 8 * (reg >> 2) + 4 * q;
            dst[(n0 + row) * 4 + h] = c2[reg];
        }
    }
}

// ---- exclusive scan of 1563 bucket counts ----
__global__ __launch_bounds__(1024) void k_bscan(const int* __restrict__ bcnt,
                                                int* __restrict__ bbase, int* __restrict__ bcursor)
{
    int t = threadIdx.x;
    int i0 = 2 * t, i1 = 2 * t + 1;
    int a = (i0 < NBK) ? bcnt[i0] : 0;
    int b = (i1 < NBK) ? bcnt[i1] : 0;
    int s = a + b;
    int lane = t & 63, wid = t >> 6;
    int sc = s;
#pragma unroll
    for (int off = 1; off < 64; off <<= 1) {
        int u = __shfl_up(sc, off, 64);
        if (lane >= off) sc += u;
    }
    __shared__ int wsum[16];
    if (lane == 63) wsum[wid] = sc;
    __syncthreads();
    int woff = 0;
    for (int k = 0; k < wid; ++k) woff += wsum[k];
    int excl = sc - s + woff;
    if (i0 < NBK) { bbase[i0] = excl;     bcursor[i0] = excl; }
    if (i1 < NBK) { bbase[i1] = excl + a; bcursor[i1] = excl + a; }
}

// ---- bin edges by dst bucket (proven single-pass) ----
__global__ __launch_bounds__(BS) void k_bscat(const int* __restrict__ ei,
                                              int* __restrict__ bcursor, int* __restrict__ bin)
{
    __shared__ int cnt[NBK];
    __shared__ int base[NBK];
    int t = threadIdx.x;
    for (int i = t; i < NBK; i += BS) cnt[i] = 0;
    __syncthreads();
    int blk = blockIdx.x * (BS * 4);
    int b[4], r[4], pk[4];
#pragma unroll
    for (int k = 0; k < 4; ++k) {
        int idx = blk + k * BS + t;
        r[k] = -1;
        if (idx < ET) {
            int s, d;
            if (idx < E0) { s = ei[idx]; d = ei[E0 + idx]; } else { s = d = idx - E0; }
            b[k] = d >> 6;
            pk[k] = s | ((d & 63) << 17);
            r[k] = atomicAdd(&cnt[b[k]], 1);
        }
    }
    __syncthreads();
    for (int i = t; i < NBK; i += BS) if (cnt[i]) base[i] = atomicAdd(&bcursor[i], cnt[i]);
    __syncthreads();
#pragma unroll
    for (int k = 0; k < 4; ++k)
        if (r[k] >= 0) bin[base[b[k]] + r[k]] = pk[k];
}

// ---- k_bsort v3: per bucket, sort edges into node-CSR + precompute fp16 evs,
// PACKED: binH[h][pos] = src(17b) | half_bits(ev_h)<<17 (ev>0 -> sign bit 0,
// 15 bits lossless). Direct scatter to global (bucket window 4.3KB, L2-local,
// lines fully dirtied). binH0 aliases bin (raw staged first). LDS 7.7KB. ----
__global__ __launch_bounds__(256) void k_bsort(
    int* __restrict__ bin, const int* __restrict__ bbase, const int* __restrict__ bcnt,
    const float* __restrict__ asr, const float* __restrict__ adr,
    int* __restrict__ binH1, int* __restrict__ binH2, int* __restrict__ binH3,
    int* __restrict__ A)
{
    __shared__ int raw[CAP];
    __shared__ float adl[256];
    __shared__ int deg[64], cur[64];
    int b = blockIdx.x, t = threadIdx.x;
    int beg = bbase[b], cnt = bcnt[b];
    if (cnt > CAP) cnt = CAP;           // 13+ sigma, never taken
    if (t < 64) deg[t] = 0;
    {
        int gi = b * 256 + t;
        adl[t] = (gi < NN * 4) ? adr[gi] : 0.f;
    }
    for (int i = t; i < cnt; i += 256) raw[i] = bin[beg + i];
    __syncthreads();
    for (int i = t; i < cnt; i += 256) atomicAdd(&deg[raw[i] >> 17], 1);
    __syncthreads();
    if (t < 64) {
        int v = deg[t];
        int sc = v;
#pragma unroll
        for (int off = 1; off < 64; off <<= 1) {
            int u = __shfl_up(sc, off, 64);
            if (t >= off) sc += u;
        }
        cur[t] = sc - v;
        int n = b * 64 + t;
        if (n < NN) A[n] = beg + sc;    // inclusive -> global je
    }
    __syncthreads();
    for (int i = t; i < cnt; i += 256) {
        int e = raw[i];
        int s = e & 0x1FFFF, dl = e >> 17;
        float4 as4 = *(const float4*)(asr + s * 4);   // gather first (overlap)
        int dl4 = dl * 4;
        float a0 = as4.x + adl[dl4 + 0]; a0 = a0 > 0.f ? a0 : NEG * a0;
        float a1 = as4.y + adl[dl4 + 1]; a1 = a1 > 0.f ? a1 : NEG * a1;
        float a2 = as4.z + adl[dl4 + 2]; a2 = a2 > 0.f ? a2 : NEG * a2;
        float a3 = as4.w + adl[dl4 + 3]; a3 = a3 > 0.f ? a3 : NEG * a3;
        int q0 = (int)__half_as_ushort(__float2half(__expf(a0)));
        int q1 = (int)__half_as_ushort(__float2half(__expf(a1)));
        int q2 = (int)__half_as_ushort(__float2half(__expf(a2)));
        int q3 = (int)__half_as_ushort(__float2half(__expf(a3)));
        int r = atomicAdd(&cur[dl], 1);
        int gp = beg + r;
        bin[gp]   = s | (q0 << 17);     // binH0 (aliases bin, raw already staged)
        binH1[gp] = s | (q1 << 17);
        binH2[gp] = s | (q2 << 17);
        binH3[gp] = s | (q3 << 17);
    }
}

// ---- Layer 1 aggregation: XCD head-partition + paired h-row gather.
// bid&7 -> XCD lane; head = lane>>1 (h1h slice 3.2MB, L2-resident). Per
// (node,head): 4 lanes, 2 edges/iter; lanes {0,1} read the two 16B halves of
// edge j's 32B h-row (same 64B line -> 1 lookup), lanes {2,3} edge j+1.
// R6: ONE packed staging array (6KB LDS, 1 ds_read/iter, occupancy ~100%). ----
__global__ __launch_bounds__(256) void k_e1agg(
    const int* __restrict__ binH0, const int* __restrict__ binH1,
    const int* __restrict__ binH2, const int* __restrict__ binH3,
    const int* __restrict__ A,
    const int* __restrict__ bbase, const int* __restrict__ bcnt,
    const __half* __restrict__ h1h,
    const float* __restrict__ b1, const float* __restrict__ W2,
    float* __restrict__ g)
{
    __shared__ int lw[CAP];
    int bid = blockIdx.x, t = threadIdx.x;
    int lane8 = bid & 7;
    int h = lane8 >> 1;
    int b = (bid >> 3) * 2 + (lane8 & 1);
    if (b >= NBK) return;
    int beg = bbase[b], cnt = bcnt[b];
    if (cnt > CAP) cnt = CAP;
    const int* bh = (h == 0) ? binH0 : (h == 1) ? binH1 : (h == 2) ? binH2 : binH3;
    for (int i = t; i < cnt; i += 256) lw[i] = bh[beg + i];
    __syncthreads();
    int q = t & 3, nl = t >> 2;
    int n = b * 64 + nl;
    if (n >= NN) return;
    int je = A[n] - beg;               if (je > cnt) je = cnt;
    int jb = ((n == 0) ? 0 : A[n - 1]) - beg; if (jb < 0) jb = 0;
    size_t hb = (size_t)h * NN;
    int p = q & 1, eo = q >> 1;
    float acc[8];
#pragma unroll
    for (int c = 0; c < 8; ++c) acc[c] = 0.f;
    float den = 0.f;
    for (int e = jb + eo; e < je; e += 2) {
        int w = lw[e];
        int s = w & 0x1FFFF;
        float evf = __half2float(__ushort_as_half((unsigned short)((unsigned)w >> 17)));
        den += evf;
        uint4 r0 = *(const uint4*)(h1h + (hb + s) * 16 + p * 8);
        float2 f0 = __half22float2(*(const __half2*)&r0.x);
        float2 f1 = __half22float2(*(const __half2*)&r0.y);
        float2 f2 = __half22float2(*(const __half2*)&r0.z);
        float2 f3 = __half22float2(*(const __half2*)&r0.w);
        acc[0] += evf * f0.x; acc[1] += evf * f0.y;
        acc[2] += evf * f1.x; acc[3] += evf * f1.y;
        acc[4] += evf * f2.x; acc[5] += evf * f2.y;
        acc[6] += evf * f3.x; acc[7] += evf * f3.y;
    }
#pragma unroll
    for (int c = 0; c < 8; ++c) acc[c] += __shfl_xor(acc[c], 2);  // merge edge parities
    den += __shfl_xor(den, 2);         // lanes {p, p+2} hold the two parities
    float inv = 1.f / (den + EPSV);
    const float* bp = b1 + h * 16 + p * 8;
    const float* wp = W2 + h * 16 + p * 8;
    float gv = 0.f;
#pragma unroll
    for (int c = 0; c < 8; ++c) {
        float v = acc[c] * inv + bp[c];
        v = v > 0.f ? v : __expf(v) - 1.f;
        gv += v * wp[c];
    }
    gv += __shfl_xor(gv, 1);           // merge channel halves
    if (q == 0) atomicAdd(&g[n], gv);
}

// ---- Layer 2 aggregation: prebuilt node CSR via binH0 (mask 17b); g L2-res. ----
__global__ __launch_bounds__(256) void k_e2agg(
    const int* __restrict__ binH0, const int* __restrict__ A,
    const int* __restrict__ bbase, const int* __restrict__ bcnt,
    const float* __restrict__ g, const float* __restrict__ as2,
    const float* __restrict__ ad2, const float* __restrict__ b2,
    float* __restrict__ out)
{
    __shared__ int lcsr[CAP];
    int b = blockIdx.x, t = threadIdx.x;
    int beg = bbase[b], cnt = bcnt[b];
    if (cnt > CAP) cnt = CAP;
    for (int i = t; i < cnt; i += 256) lcsr[i] = binH0[beg + i] & 0x1FFFF;
    __syncthreads();
    int p = t & 3, nl = t >> 2;
    int n = b * 64 + nl;
    if (n >= NN) return;
    int je = A[n] - beg;               if (je > cnt) je = cnt;
    int jb = ((n == 0) ? 0 : A[n - 1]) - beg; if (jb < 0) jb = 0;
    float cs = as2[0];
    float gdcd = g[n] * ad2[0];
    float acc = 0.f, den = 0.f;
    for (int j = jb + p; j < je; j += 4) {
        float gz = g[lcsr[j]];
        float a = gz * cs + gdcd;
        a = a > 0.f ? a : NEG * a;
        float ev = __expf(a);
        den += ev;
        acc += ev * gz;
    }
    acc += __shfl_xor(acc, 1); den += __shfl_xor(den, 1);
    acc += __shfl_xor(acc, 2); den += __shfl_xor(den, 2);
    if (p == 0) out[n] = acc / (den + EPSV) + b2[0];
}

extern "C" void kernel_launch(void* const* d_in, const int* in_sizes, int n_in,
                              void* d_out, int out_size, void* d_ws, size_t ws_size,
                              hipStream_t stream)
{
    const float* x   = (const float*)d_in[0];
    const int*   ei  = (const int*)d_in[1];
    const float* W1  = (const float*)d_in[2];
    const float* as1 = (const float*)d_in[3];
    const float* ad1 = (const float*)d_in[4];
    const float* b1  = (const float*)d_in[5];
    const float* W2  = (const float*)d_in[6];
    const float* as2 = (const float*)d_in[7];
    const float* ad2 = (const float*)d_in[8];
    const float* b2  = (const float*)d_in[9];
    float* out = (float*)d_out;

    // workspace layout (4-byte slots)
    int*   iw      = (int*)d_ws;
    float* fw      = (float*)d_ws;
    int*   bcnt    = iw;                    //     1,664
    int*   bbase   = iw + 1664;             //     1,664
    int*   bcursor = iw + 3328;             //     1,664
    int*   A       = iw + 4992;             //   100,352  (inclusive je offsets)
    int*   bin     = iw + 105344;           // 1,700,000  (pk -> packed head0 in place)
    int*   binH1   = iw + 1805344;          // 1,700,000  (src | ev_h<<17)
    int*   binH2   = iw + 3505344;          // 1,700,000
    int*   binH3   = iw + 5205344;          // 1,700,000
    float* asr     = fw + 6905344;          //   400,000  ([n][4] 16B rows)
    float* adr     = fw + 7305344;          //   400,000
    float* g       = fw + 7705344;          //   100,032
    __half* h1hQ   = (__half*)(fw + 7805376); // 6.4M halves, head-major [h][n][16]
    // total 11,005,376 slots = 44.0 MB

    hipMemsetAsync(bcnt, 0, NBK * sizeof(int), stream);
    hipMemsetAsync(g, 0, NN * sizeof(float), stream);

    k_g1bc  <<<GEMM_NB + BC_NB, 256, 0, stream>>>(x, ei, W1, as1, ad1,
                                                  h1hQ, asr, adr, bcnt);
    k_bscan <<<1, 1024, 0, stream>>>(bcnt, bbase, bcursor);
    k_bscat <<<NBLK4, BS, 0, stream>>>(ei, bcursor, bin);
    k_bsort <<<NBK, 256, 0, stream>>>(bin, bbase, bcnt, asr, adr,
                                      binH1, binH2, binH3, A);
    k_e1agg <<<E1_NB, 256, 0, stream>>>(bin, binH1, binH2, binH3, A, bbase, bcnt,
                                        h1hQ, b1, W2, g);
    k_e2agg <<<NBK, 256, 0, stream>>>(bin, A, bbase, bcnt, g, as2, ad2, b2, out);
}

// Round 7
// 221.836 us; speedup vs baseline: 1.0125x; 1.0125x over previous
//
#include <hip/hip_runtime.h>
#include <hip/hip_fp16.h>

#define NN   100000
#define E0   1600000
#define ET   1700000
#define NEG  0.2f
#define EPSV 1e-16f
#define NBK  1563           // dst buckets of 64 node ids (ceil(NN/64))
#define CAP  1536           // LDS edge-list capacity (bucket mean 1088, sigma 33)
#define BS   1024
#define NBLK4 ((ET + 4 * BS - 1) / (4 * BS))   // 416 (single-pass bscat)
#define GEMM_NB 782         // ceil(NN/32/4) tiles of 4 waves
#define BC_NB   416         // bcount blocks in merged kernel (256 thr, 16 e/thr)
#define E1_NB   6256        // 782 rounds x 8 XCD lanes (head = lane>>1, 2 buckets/round)

typedef _Float16 half8 __attribute__((ext_vector_type(8)));
typedef float f32x16 __attribute__((ext_vector_type(16)));

// ---- MERGED: blocks [0,782) = MFMA GEMM; blocks [782,1198) = bucket count.
// h1h head-major quad [h][n][16] (XCD slicing); asrcm/adrm HEAD-MAJOR [h][n]
// (R7: e1agg computes ev on the fly from the L2-resident 0.4MB head slice). ----
__global__ __launch_bounds__(256) void k_g1bc(
    const float* __restrict__ x, const int* __restrict__ ei,
    const float* __restrict__ W1, const float* __restrict__ as1,
    const float* __restrict__ ad1,
    __half* __restrict__ h1h, float* __restrict__ asrcm, float* __restrict__ adrm,
    int* __restrict__ bcnt)
{
    int t = threadIdx.x;
    if (blockIdx.x >= GEMM_NB) {
        __shared__ int cnt[NBK];
        for (int i = t; i < NBK; i += 256) cnt[i] = 0;
        __syncthreads();
        int base = (blockIdx.x - GEMM_NB) * (256 * 16);
#pragma unroll
        for (int k = 0; k < 16; ++k) {
            int idx = base + k * 256 + t;
            if (idx < ET) {
                int d = (idx < E0) ? ei[E0 + idx] : (idx - E0);
                atomicAdd(&cnt[d >> 6], 1);
            }
        }
        __syncthreads();
        for (int i = t; i < NBK; i += 256) if (cnt[i]) atomicAdd(&bcnt[i], cnt[i]);
        return;
    }
    // ---------------- GEMM body (R14 math, verified) ----------------
    __shared__ float Wl[4096];
    __shared__ float Ul[512];
    for (int i = t; i < 4096; i += 256) Wl[i] = W1[i];
    __syncthreads();
    if (t < 64) {
        int k = t;
#pragma unroll
        for (int h = 0; h < 4; ++h) {
            float su = 0.f, du = 0.f;
#pragma unroll
            for (int c = 0; c < 16; ++c) {
                float w = Wl[k * 64 + h * 16 + c];
                su += w * as1[h * 16 + c];
                du += w * ad1[h * 16 + c];
            }
            Ul[k * 8 + h] = su;
            Ul[k * 8 + 4 + h] = du;
        }
    }
    __syncthreads();
    int lane = t & 63, wv = t >> 6;
    int col = lane & 31, q = lane >> 5;
    half8 bf0[4], bf1[4], bf2[4];
#pragma unroll
    for (int kc = 0; kc < 4; ++kc) {
#pragma unroll
        for (int j = 0; j < 8; ++j) {
            int k = kc * 16 + q * 8 + j;
            bf0[kc][j] = (_Float16)Wl[k * 64 + col];
            bf1[kc][j] = (_Float16)Wl[k * 64 + 32 + col];
            bf2[kc][j] = (col < 8) ? (_Float16)Ul[k * 8 + col] : (_Float16)0.f;
        }
    }
    int tile = blockIdx.x * 4 + wv;
    int n0 = tile * 32;
    if (n0 >= NN) return;
    half8 af[4];
    const float* xrow = x + (size_t)(n0 + col) * 64;
#pragma unroll
    for (int kc = 0; kc < 4; ++kc) {
        float4 xa = *(const float4*)(xrow + kc * 16 + q * 8);
        float4 xb = *(const float4*)(xrow + kc * 16 + q * 8 + 4);
        af[kc][0] = (_Float16)xa.x; af[kc][1] = (_Float16)xa.y;
        af[kc][2] = (_Float16)xa.z; af[kc][3] = (_Float16)xa.w;
        af[kc][4] = (_Float16)xb.x; af[kc][5] = (_Float16)xb.y;
        af[kc][6] = (_Float16)xb.z; af[kc][7] = (_Float16)xb.w;
    }
    f32x16 c0 = {}, c1 = {}, c2 = {};
#pragma unroll
    for (int kc = 0; kc < 4; ++kc) {
        c0 = __builtin_amdgcn_mfma_f32_32x32x16_f16(af[kc], bf0[kc], c0, 0, 0, 0);
        c1 = __builtin_amdgcn_mfma_f32_32x32x16_f16(af[kc], bf1[kc], c1, 0, 0, 0);
        c2 = __builtin_amdgcn_mfma_f32_32x32x16_f16(af[kc], bf2[kc], c2, 0, 0, 0);
    }
    // head-major h1h: c0 -> heads {0,1}, c1 -> heads {2,3}; rows of 16 halves (32B)
    int hA = col >> 4, cc = col & 15;
#pragma unroll
    for (int reg = 0; reg < 16; ++reg) {
        int row = (reg & 3) + 8 * (reg >> 2) + 4 * q;
        size_t n = (size_t)(n0 + row);
        h1h[((size_t)hA * NN + n) * 16 + cc]       = __float2half(c0[reg]);
        h1h[((size_t)(hA + 2) * NN + n) * 16 + cc] = __float2half(c1[reg]);
    }
    if (col < 8) {
        float* dst = (col < 4) ? asrcm : adrm;
        int h = col & 3;
#pragma unroll
        for (int reg = 0; reg < 16; ++reg) {
            int row = (reg & 3) + 8 * (reg >> 2) + 4 * q;
            dst[(size_t)h * NN + (n0 + row)] = c2[reg];
        }
    }
}

// ---- exclusive scan of 1563 bucket counts ----
__global__ __launch_bounds__(1024) void k_bscan(const int* __restrict__ bcnt,
                                                int* __restrict__ bbase, int* __restrict__ bcursor)
{
    int t = threadIdx.x;
    int i0 = 2 * t, i1 = 2 * t + 1;
    int a = (i0 < NBK) ? bcnt[i0] : 0;
    int b = (i1 < NBK) ? bcnt[i1] : 0;
    int s = a + b;
    int lane = t & 63, wid = t >> 6;
    int sc = s;
#pragma unroll
    for (int off = 1; off < 64; off <<= 1) {
        int u = __shfl_up(sc, off, 64);
        if (lane >= off) sc += u;
    }
    __shared__ int wsum[16];
    if (lane == 63) wsum[wid] = sc;
    __syncthreads();
    int woff = 0;
    for (int k = 0; k < wid; ++k) woff += wsum[k];
    int excl = sc - s + woff;
    if (i0 < NBK) { bbase[i0] = excl;     bcursor[i0] = excl; }
    if (i1 < NBK) { bbase[i1] = excl + a; bcursor[i1] = excl + a; }
}

// ---- bin edges by dst bucket (proven single-pass) ----
__global__ __launch_bounds__(BS) void k_bscat(const int* __restrict__ ei,
                                              int* __restrict__ bcursor, int* __restrict__ bin)
{
    __shared__ int cnt[NBK];
    __shared__ int base[NBK];
    int t = threadIdx.x;
    for (int i = t; i < NBK; i += BS) cnt[i] = 0;
    __syncthreads();
    int blk = blockIdx.x * (BS * 4);
    int b[4], r[4], pk[4];
#pragma unroll
    for (int k = 0; k < 4; ++k) {
        int idx = blk + k * BS + t;
        r[k] = -1;
        if (idx < ET) {
            int s, d;
            if (idx < E0) { s = ei[idx]; d = ei[E0 + idx]; } else { s = d = idx - E0; }
            b[k] = d >> 6;
            pk[k] = s | ((d & 63) << 17);
            r[k] = atomicAdd(&cnt[b[k]], 1);
        }
    }
    __syncthreads();
    for (int i = t; i < NBK; i += BS) if (cnt[i]) base[i] = atomicAdd(&bcursor[i], cnt[i]);
    __syncthreads();
#pragma unroll
    for (int k = 0; k < 4; ++k)
        if (r[k] >= 0) bin[base[b[k]] + r[k]] = pk[k];
}

// ---- k_bsort (R7: sort-only, R3-proven). Per bucket: build node-level CSR
// once in LDS, write back in-place (coalesced, pure src), emit A[n] = je. ----
__global__ __launch_bounds__(256) void k_bsort(
    int* __restrict__ bin, const int* __restrict__ bbase, const int* __restrict__ bcnt,
    int* __restrict__ A)
{
    __shared__ int raw[CAP];
    __shared__ int srt[CAP];
    __shared__ int deg[64], cur[64];
    int b = blockIdx.x, t = threadIdx.x;
    int beg = bbase[b], cnt = bcnt[b];
    if (cnt > CAP) cnt = CAP;   // 13+ sigma, never taken
    if (t < 64) deg[t] = 0;
    for (int i = t; i < cnt; i += 256) raw[i] = bin[beg + i];
    __syncthreads();
    for (int i = t; i < cnt; i += 256) atomicAdd(&deg[raw[i] >> 17], 1);
    __syncthreads();
    if (t < 64) {
        int v = deg[t];
        int sc = v;
#pragma unroll
        for (int off = 1; off < 64; off <<= 1) {
            int u = __shfl_up(sc, off, 64);
            if (t >= off) sc += u;
        }
        cur[t] = sc - v;
        int n = b * 64 + t;
        if (n < NN) A[n] = beg + sc;    // inclusive -> global je
    }
    __syncthreads();
    for (int i = t; i < cnt; i += 256) {
        int e = raw[i];
        int r = atomicAdd(&cur[e >> 17], 1);
        srt[r] = e & 0x1FFFF;           // src only
    }
    __syncthreads();
    for (int i = t; i < cnt; i += 256) bin[beg + i] = srt[i];
}

// ---- Layer 1 aggregation: XCD head-partition + pair-gather + on-the-fly ev.
// bid&7 -> XCD lane; head = lane>>1 (h1h slice 3.2MB + asrcm slice 0.4MB,
// both L2-resident). Per (node,head): 4 lanes; p=q&1 picks the 16B h-row
// half (same 64B line), eo=q>>1 the edge parity. ev computed from asrcm
// broadcast gather. R7: explicit UNROLL-2 (2 edges in flight per lane) to
// break the ~500cy serial ds_read->gather chain (R6 was latency-bound:
// 0.24 lines/cy/CU, 716 GB/s, nothing saturated). ----
__global__ __launch_bounds__(256) void k_e1agg(
    const int* __restrict__ bin, const int* __restrict__ A,
    const int* __restrict__ bbase, const int* __restrict__ bcnt,
    const float* __restrict__ asrcm, const float* __restrict__ adrm,
    const __half* __restrict__ h1h,
    const float* __restrict__ b1, const float* __restrict__ W2,
    float* __restrict__ g)
{
    __shared__ int lw[CAP];
    int bid = blockIdx.x, t = threadIdx.x;
    int lane8 = bid & 7;
    int h = lane8 >> 1;
    int b = (bid >> 3) * 2 + (lane8 & 1);
    if (b >= NBK) return;
    int beg = bbase[b], cnt = bcnt[b];
    if (cnt > CAP) cnt = CAP;
    for (int i = t; i < cnt; i += 256) lw[i] = bin[beg + i];
    __syncthreads();
    int q = t & 3, nl = t >> 2;
    int n = b * 64 + nl;
    if (n >= NN) return;
    int je = A[n] - beg;               if (je > cnt) je = cnt;
    int jb = ((n == 0) ? 0 : A[n - 1]) - beg; if (jb < 0) jb = 0;
    size_t hb = (size_t)h * NN;
    int p = q & 1, eo = q >> 1;
    float adv = adrm[hb + n];
    float acc[8];
#pragma unroll
    for (int c = 0; c < 8; ++c) acc[c] = 0.f;
    float den = 0.f;

#define ACC1(avv, rr) { \
        float a = avv + adv; a = a > 0.f ? a : NEG * a; \
        float ev = __expf(a); den += ev; \
        float2 f0 = __half22float2(*(const __half2*)&rr.x); \
        float2 f1 = __half22float2(*(const __half2*)&rr.y); \
        float2 f2 = __half22float2(*(const __half2*)&rr.z); \
        float2 f3 = __half22float2(*(const __half2*)&rr.w); \
        acc[0] += ev * f0.x; acc[1] += ev * f0.y; \
        acc[2] += ev * f1.x; acc[3] += ev * f1.y; \
        acc[4] += ev * f2.x; acc[5] += ev * f2.y; \
        acc[6] += ev * f3.x; acc[7] += ev * f3.y; }

    int e = jb + eo;
    for (; e + 2 < je; e += 4) {       // unroll-2: edges e and e+2 in flight
        int s0 = lw[e], s1 = lw[e + 2];
        float av0 = asrcm[hb + s0];
        float av1 = asrcm[hb + s1];
        uint4 r0 = *(const uint4*)(h1h + (hb + s0) * 16 + p * 8);
        uint4 r1 = *(const uint4*)(h1h + (hb + s1) * 16 + p * 8);
        ACC1(av0, r0)
        ACC1(av1, r1)
    }
    if (e < je) {
        int s0 = lw[e];
        float av0 = asrcm[hb + s0];
        uint4 r0 = *(const uint4*)(h1h + (hb + s0) * 16 + p * 8);
        ACC1(av0, r0)
    }
#undef ACC1

#pragma unroll
    for (int c = 0; c < 8; ++c) acc[c] += __shfl_xor(acc[c], 2);  // merge edge parities
    den += __shfl_xor(den, 2);
    float inv = 1.f / (den + EPSV);
    const float* bp = b1 + h * 16 + p * 8;
    const float* wp = W2 + h * 16 + p * 8;
    float gv = 0.f;
#pragma unroll
    for (int c = 0; c < 8; ++c) {
        float v = acc[c] * inv + bp[c];
        v = v > 0.f ? v : __expf(v) - 1.f;
        gv += v * wp[c];
    }
    gv += __shfl_xor(gv, 1);           // merge channel halves
    if (q == 0) atomicAdd(&g[n], gv);
}

// ---- Layer 2 aggregation: prebuilt node CSR (pure src); g L2-resident.
// R7: unroll-2 on the gather loop. ----
__global__ __launch_bounds__(256) void k_e2agg(
    const int* __restrict__ bin, const int* __restrict__ A,
    const int* __restrict__ bbase, const int* __restrict__ bcnt,
    const float* __restrict__ g, const float* __restrict__ as2,
    const float* __restrict__ ad2, const float* __restrict__ b2,
    float* __restrict__ out)
{
    __shared__ int lcsr[CAP];
    int b = blockIdx.x, t = threadIdx.x;
    int beg = bbase[b], cnt = bcnt[b];
    if (cnt > CAP) cnt = CAP;
    for (int i = t; i < cnt; i += 256) lcsr[i] = bin[beg + i];
    __syncthreads();
    int p = t & 3, nl = t >> 2;
    int n = b * 64 + nl;
    if (n >= NN) return;
    int je = A[n] - beg;               if (je > cnt) je = cnt;
    int jb = ((n == 0) ? 0 : A[n - 1]) - beg; if (jb < 0) jb = 0;
    float cs = as2[0];
    float gdcd = g[n] * ad2[0];
    float acc = 0.f, den = 0.f;

#define ACC2(gz) { \
        float a = gz * cs + gdcd; a = a > 0.f ? a : NEG * a; \
        float ev = __expf(a); den += ev; acc += ev * gz; }

    int j = jb + p;
    for (; j + 4 < je; j += 8) {
        int s0 = lcsr[j], s1 = lcsr[j + 4];
        float g0 = g[s0], g1 = g[s1];
        ACC2(g0)
        ACC2(g1)
    }
    if (j < je) {
        float g0 = g[lcsr[j]];
        ACC2(g0)
    }
#undef ACC2

    acc += __shfl_xor(acc, 1); den += __shfl_xor(den, 1);
    acc += __shfl_xor(acc, 2); den += __shfl_xor(den, 2);
    if (p == 0) out[n] = acc / (den + EPSV) + b2[0];
}

extern "C" void kernel_launch(void* const* d_in, const int* in_sizes, int n_in,
                              void* d_out, int out_size, void* d_ws, size_t ws_size,
                              hipStream_t stream)
{
    const float* x   = (const float*)d_in[0];
    const int*   ei  = (const int*)d_in[1];
    const float* W1  = (const float*)d_in[2];
    const float* as1 = (const float*)d_in[3];
    const float* ad1 = (const float*)d_in[4];
    const float* b1  = (const float*)d_in[5];
    const float* W2  = (const float*)d_in[6];
    const float* as2 = (const float*)d_in[7];
    const float* ad2 = (const float*)d_in[8];
    const float* b2  = (const float*)d_in[9];
    float* out = (float*)d_out;

    // workspace layout (4-byte slots)
    int*   iw      = (int*)d_ws;
    float* fw      = (float*)d_ws;
    int*   bcnt    = iw;                    //     1,664
    int*   bbase   = iw + 1664;             //     1,664
    int*   bcursor = iw + 3328;             //     1,664
    int*   A       = iw + 4992;             //   100,352  (inclusive je offsets)
    int*   bin     = iw + 105344;           // 1,700,000  (pk -> sorted src in place)
    float* asrcm   = fw + 1805344;          //   400,000  (head-major [h][n])
    float* adrm    = fw + 2205344;          //   400,000  (head-major [h][n])
    float* g       = fw + 2605344;          //   100,032
    __half* h1hQ   = (__half*)(fw + 2705376); // 6.4M halves, head-major [h][n][16]
    // total 5,905,376 slots = 23.6 MB

    hipMemsetAsync(bcnt, 0, NBK * sizeof(int), stream);
    hipMemsetAsync(g, 0, NN * sizeof(float), stream);

    k_g1bc  <<<GEMM_NB + BC_NB, 256, 0, stream>>>(x, ei, W1, as1, ad1,
                                                  h1hQ, asrcm, adrm, bcnt);
    k_bscan <<<1, 1024, 0, stream>>>(bcnt, bbase, bcursor);
    k_bscat <<<NBLK4, BS, 0, stream>>>(ei, bcursor, bin);
    k_bsort <<<NBK, 256, 0, stream>>>(bin, bbase, bcnt, A);
    k_e1agg <<<E1_NB, 256, 0, stream>>>(bin, A, bbase, bcnt, asrcm, adrm,
                                        h1hQ, b1, W2, g);
    k_e2agg <<<NBK, 256, 0, stream>>>(bin, A, bbase, bcnt, g, as2, ad2, b2, out);
}

// Round 8
// 198.410 us; speedup vs baseline: 1.1321x; 1.1181x over previous
//
#include <hip/hip_runtime.h>
#include <hip/hip_fp16.h>

#define NN   100000
#define E0   1600000
#define ET   1700000
#define NEG  0.2f
#define EPSV 1e-16f
#define NBK  1563           // dst buckets of 64 node ids (ceil(NN/64))
#define CAP  1536           // LDS edge-list capacity (bucket mean 1088, sigma 33)
#define BS   1024
#define SCAT_NB 104         // R8: 16384 edges/block (16/thr) -> 4x fewer dirty lines
#define GEMM_NB 782         // ceil(NN/32/4) tiles of 4 waves
#define BC_NB   104         // bcount blocks (256 thr, 64 e/thr)

typedef _Float16 half8 __attribute__((ext_vector_type(8)));
typedef float f32x16 __attribute__((ext_vector_type(16)));

// ---- MERGED: blocks [0,782) = MFMA GEMM (NODE-major outputs, R0-proven);
//      blocks [782,886) = bucket count (16K edges each). ----
__global__ __launch_bounds__(256) void k_g1bc(
    const float* __restrict__ x, const int* __restrict__ ei,
    const float* __restrict__ W1, const float* __restrict__ as1,
    const float* __restrict__ ad1,
    __half* __restrict__ h1h, float* __restrict__ asrc1, float* __restrict__ adst1,
    int* __restrict__ bcnt)
{
    int t = threadIdx.x;
    if (blockIdx.x >= GEMM_NB) {
        __shared__ int cnt[NBK];
        for (int i = t; i < NBK; i += 256) cnt[i] = 0;
        __syncthreads();
        int base = (blockIdx.x - GEMM_NB) * (256 * 64);
        for (int k = 0; k < 64; ++k) {
            int idx = base + k * 256 + t;
            if (idx < ET) {
                int d = (idx < E0) ? ei[E0 + idx] : (idx - E0);
                atomicAdd(&cnt[d >> 6], 1);
            }
        }
        __syncthreads();
        for (int i = t; i < NBK; i += 256) if (cnt[i]) atomicAdd(&bcnt[i], cnt[i]);
        return;
    }
    // ---------------- GEMM body (R14 math, verified R0) ----------------
    __shared__ float Wl[4096];
    __shared__ float Ul[512];
    for (int i = t; i < 4096; i += 256) Wl[i] = W1[i];
    __syncthreads();
    if (t < 64) {
        int k = t;
#pragma unroll
        for (int h = 0; h < 4; ++h) {
            float su = 0.f, du = 0.f;
#pragma unroll
            for (int c = 0; c < 16; ++c) {
                float w = Wl[k * 64 + h * 16 + c];
                su += w * as1[h * 16 + c];
                du += w * ad1[h * 16 + c];
            }
            Ul[k * 8 + h] = su;
            Ul[k * 8 + 4 + h] = du;
        }
    }
    __syncthreads();
    int lane = t & 63, wv = t >> 6;
    int col = lane & 31, q = lane >> 5;
    half8 bf0[4], bf1[4], bf2[4];
#pragma unroll
    for (int kc = 0; kc < 4; ++kc) {
#pragma unroll
        for (int j = 0; j < 8; ++j) {
            int k = kc * 16 + q * 8 + j;
            bf0[kc][j] = (_Float16)Wl[k * 64 + col];
            bf1[kc][j] = (_Float16)Wl[k * 64 + 32 + col];
            bf2[kc][j] = (col < 8) ? (_Float16)Ul[k * 8 + col] : (_Float16)0.f;
        }
    }
    int tile = blockIdx.x * 4 + wv;
    int n0 = tile * 32;
    if (n0 >= NN) return;
    half8 af[4];
    const float* xrow = x + (size_t)(n0 + col) * 64;
#pragma unroll
    for (int kc = 0; kc < 4; ++kc) {
        float4 xa = *(const float4*)(xrow + kc * 16 + q * 8);
        float4 xb = *(const float4*)(xrow + kc * 16 + q * 8 + 4);
        af[kc][0] = (_Float16)xa.x; af[kc][1] = (_Float16)xa.y;
        af[kc][2] = (_Float16)xa.z; af[kc][3] = (_Float16)xa.w;
        af[kc][4] = (_Float16)xb.x; af[kc][5] = (_Float16)xb.y;
        af[kc][6] = (_Float16)xb.z; af[kc][7] = (_Float16)xb.w;
    }
    f32x16 c0 = {}, c1 = {}, c2 = {};
#pragma unroll
    for (int kc = 0; kc < 4; ++kc) {
        c0 = __builtin_amdgcn_mfma_f32_32x32x16_f16(af[kc], bf0[kc], c0, 0, 0, 0);
        c1 = __builtin_amdgcn_mfma_f32_32x32x16_f16(af[kc], bf1[kc], c1, 0, 0, 0);
        c2 = __builtin_amdgcn_mfma_f32_32x32x16_f16(af[kc], bf2[kc], c2, 0, 0, 0);
    }
#pragma unroll
    for (int reg = 0; reg < 16; ++reg) {
        int row = (reg & 3) + 8 * (reg >> 2) + 4 * q;
        h1h[(size_t)(n0 + row) * 64 + col]      = __float2half(c0[reg]);
        h1h[(size_t)(n0 + row) * 64 + 32 + col] = __float2half(c1[reg]);
    }
    if (col < 8) {
        float* dst = (col < 4) ? asrc1 : adst1;
        int h = col & 3;
#pragma unroll
        for (int reg = 0; reg < 16; ++reg) {
            int row = (reg & 3) + 8 * (reg >> 2) + 4 * q;
            dst[(n0 + row) * 4 + h] = c2[reg];
        }
    }
}

// ---- exclusive scan of 1563 bucket counts ----
__global__ __launch_bounds__(1024) void k_bscan(const int* __restrict__ bcnt,
                                                int* __restrict__ bbase, int* __restrict__ bcursor)
{
    int t = threadIdx.x;
    int i0 = 2 * t, i1 = 2 * t + 1;
    int a = (i0 < NBK) ? bcnt[i0] : 0;
    int b = (i1 < NBK) ? bcnt[i1] : 0;
    int s = a + b;
    int lane = t & 63, wid = t >> 6;
    int sc = s;
#pragma unroll
    for (int off = 1; off < 64; off <<= 1) {
        int u = __shfl_up(sc, off, 64);
        if (lane >= off) sc += u;
    }
    __shared__ int wsum[16];
    if (lane == 63) wsum[wid] = sc;
    __syncthreads();
    int woff = 0;
    for (int k = 0; k < wid; ++k) woff += wsum[k];
    int excl = sc - s + woff;
    if (i0 < NBK) { bbase[i0] = excl;     bcursor[i0] = excl; }
    if (i1 < NBK) { bbase[i1] = excl + a; bcursor[i1] = excl + a; }
}

// ---- bin edges by dst bucket. R8: 16384 edges/block so each (block,bucket)
// run is ~10.5 edges = 42B contiguous -> ~4x fewer dirty 64B lines than the
// 416-block version; cursor atomics 600K -> 150K. ----
__global__ __launch_bounds__(BS) void k_bscat(const int* __restrict__ ei,
                                              int* __restrict__ bcursor, int* __restrict__ bin)
{
    __shared__ int cnt[NBK];
    __shared__ int base[NBK];
    int t = threadIdx.x;
    for (int i = t; i < NBK; i += BS) cnt[i] = 0;
    __syncthreads();
    int blk = blockIdx.x * (BS * 16);
    int b[16], r[16], pk[16];
#pragma unroll
    for (int k = 0; k < 16; ++k) {
        int idx = blk + k * BS + t;
        r[k] = -1;
        if (idx < ET) {
            int s, d;
            if (idx < E0) { s = ei[idx]; d = ei[E0 + idx]; } else { s = d = idx - E0; }
            b[k] = d >> 6;
            pk[k] = s | ((d & 63) << 17);
            r[k] = atomicAdd(&cnt[b[k]], 1);
        }
    }
    __syncthreads();
    for (int i = t; i < NBK; i += BS) if (cnt[i]) base[i] = atomicAdd(&bcursor[i], cnt[i]);
    __syncthreads();
#pragma unroll
    for (int k = 0; k < 16; ++k)
        if (r[k] >= 0) bin[base[b[k]] + r[k]] = pk[k];
}

// ---- Layer 1 aggregation (R0-proven node-major form) + CSR export.
// Per bucket: rebuild node CSR in LDS (deg/scan/scatter), then 4 head-lanes
// per node aggregate (2 line-lookups per edge, ~2.5 TB/s L2-fill wall).
// R8: writes sorted src list back to bin + A[n]=je so e2agg skips rebuild;
// g is plain-stored (no memset/atomics). ----
__global__ __launch_bounds__(256) void k_e1agg(
    int* __restrict__ bin, const int* __restrict__ bbase, const int* __restrict__ bcnt,
    const float* __restrict__ asrc1, const float* __restrict__ adst1,
    const __half* __restrict__ h1h, const float* __restrict__ b1,
    const float* __restrict__ W2, float* __restrict__ g, int* __restrict__ A)
{
    __shared__ int lcsr[CAP];
    __shared__ int deg[64], cur[64];
    int b = blockIdx.x;
    int t = threadIdx.x;
    int beg = bbase[b], cnt = bcnt[b];
    if (cnt > CAP) cnt = CAP;   // 13+ sigma, never taken
    if (t < 64) deg[t] = 0;
    __syncthreads();
    for (int i = t; i < cnt; i += 256) atomicAdd(&deg[bin[beg + i] >> 17], 1);
    __syncthreads();
    if (t < 64) {
        int v = deg[t];
        int sc = v;
#pragma unroll
        for (int off = 1; off < 64; off <<= 1) {
            int u = __shfl_up(sc, off, 64);
            if (t >= off) sc += u;
        }
        cur[t] = sc - v;
        int n = b * 64 + t;
        if (n < NN) A[n] = beg + sc;           // inclusive -> global je
    }
    __syncthreads();
    for (int i = t; i < cnt; i += 256) {
        int e = bin[beg + i];
        int r = atomicAdd(&cur[e >> 17], 1);
        lcsr[r] = e & 0x1FFFF;
    }
    __syncthreads();
    for (int i = t; i < cnt; i += 256) bin[beg + i] = lcsr[i];   // sorted export
    int hh = t & 3;
    int nl = t >> 2;
    int n = b * 64 + nl;
    if (n >= NN) return;
    int je = cur[nl];
    int jb = je - deg[nl];
    float ad = adst1[n * 4 + hh];
    float acc[16];
#pragma unroll
    for (int c = 0; c < 16; ++c) acc[c] = 0.f;
    float den = 0.f;
    for (int j = jb; j < je; ++j) {
        int s = lcsr[j];
        float as = asrc1[s * 4 + hh];
        float a = as + ad; a = a > 0.f ? a : NEG * a;
        float ev = __expf(a);
        den += ev;
        const uint4* hp = (const uint4*)(h1h + (size_t)s * 64 + hh * 16);
        uint4 r0 = hp[0], r1 = hp[1];
#define U4ACC(r, base) { \
        float2 f0 = __half22float2(*(const __half2*)&r.x); \
        float2 f1 = __half22float2(*(const __half2*)&r.y); \
        float2 f2 = __half22float2(*(const __half2*)&r.z); \
        float2 f3 = __half22float2(*(const __half2*)&r.w); \
        acc[base+0] += ev * f0.x; acc[base+1] += ev * f0.y; \
        acc[base+2] += ev * f1.x; acc[base+3] += ev * f1.y; \
        acc[base+4] += ev * f2.x; acc[base+5] += ev * f2.y; \
        acc[base+6] += ev * f3.x; acc[base+7] += ev * f3.y; }
        U4ACC(r0, 0) U4ACC(r1, 8)
#undef U4ACC
    }
    float inv = 1.f / (den + EPSV);
    const float4* bp = (const float4*)(b1 + hh * 16);
    const float4* wp = (const float4*)(W2 + hh * 16);
    float gv = 0.f;
#pragma unroll
    for (int q = 0; q < 4; ++q) {
        float4 bb = bp[q], w2 = wp[q];
        float v0 = acc[4*q+0] * inv + bb.x; v0 = v0 > 0.f ? v0 : __expf(v0) - 1.f;
        float v1 = acc[4*q+1] * inv + bb.y; v1 = v1 > 0.f ? v1 : __expf(v1) - 1.f;
        float v2 = acc[4*q+2] * inv + bb.z; v2 = v2 > 0.f ? v2 : __expf(v2) - 1.f;
        float v3 = acc[4*q+3] * inv + bb.w; v3 = v3 > 0.f ? v3 : __expf(v3) - 1.f;
        gv += v0 * w2.x + v1 * w2.y + v2 * w2.z + v3 * w2.w;
    }
    gv += __shfl_xor(gv, 1);
    gv += __shfl_xor(gv, 2);
    if (hh == 0) g[n] = gv;
}

// ---- Layer 2 aggregation: prebuilt sorted CSR (no rebuild), unroll-2. ----
__global__ __launch_bounds__(256) void k_e2agg(
    const int* __restrict__ bin, const int* __restrict__ A,
    const int* __restrict__ bbase, const int* __restrict__ bcnt,
    const float* __restrict__ g, const float* __restrict__ as2,
    const float* __restrict__ ad2, const float* __restrict__ b2,
    float* __restrict__ out)
{
    __shared__ int lcsr[CAP];
    int b = blockIdx.x, t = threadIdx.x;
    int beg = bbase[b], cnt = bcnt[b];
    if (cnt > CAP) cnt = CAP;
    for (int i = t; i < cnt; i += 256) lcsr[i] = bin[beg + i];
    __syncthreads();
    int p = t & 3, nl = t >> 2;
    int n = b * 64 + nl;
    if (n >= NN) return;
    int je = A[n] - beg;                        if (je > cnt) je = cnt;
    int jb = ((n == 0) ? 0 : A[n - 1]) - beg;   if (jb < 0) jb = 0;
    float cs = as2[0];
    float gdcd = g[n] * ad2[0];
    float acc = 0.f, den = 0.f;

#define ACC2(gz) { \
        float a = gz * cs + gdcd; a = a > 0.f ? a : NEG * a; \
        float ev = __expf(a); den += ev; acc += ev * gz; }

    int j = jb + p;
    for (; j + 4 < je; j += 8) {
        int s0 = lcsr[j], s1 = lcsr[j + 4];
        float g0 = g[s0], g1 = g[s1];
        ACC2(g0)
        ACC2(g1)
    }
    if (j < je) {
        float g0 = g[lcsr[j]];
        ACC2(g0)
    }
#undef ACC2

    acc += __shfl_xor(acc, 1); den += __shfl_xor(den, 1);
    acc += __shfl_xor(acc, 2); den += __shfl_xor(den, 2);
    if (p == 0) out[n] = acc / (den + EPSV) + b2[0];
}

extern "C" void kernel_launch(void* const* d_in, const int* in_sizes, int n_in,
                              void* d_out, int out_size, void* d_ws, size_t ws_size,
                              hipStream_t stream)
{
    const float* x   = (const float*)d_in[0];
    const int*   ei  = (const int*)d_in[1];
    const float* W1  = (const float*)d_in[2];
    const float* as1 = (const float*)d_in[3];
    const float* ad1 = (const float*)d_in[4];
    const float* b1  = (const float*)d_in[5];
    const float* W2  = (const float*)d_in[6];
    const float* as2 = (const float*)d_in[7];
    const float* ad2 = (const float*)d_in[8];
    const float* b2  = (const float*)d_in[9];
    float* out = (float*)d_out;

    // workspace layout (4-byte slots)
    int*   iw      = (int*)d_ws;
    float* fw      = (float*)d_ws;
    int*   bcnt    = iw;                    //     1,664
    int*   bbase   = iw + 1664;             //     1,664
    int*   bcursor = iw + 3328;             //     1,664
    int*   A       = iw + 4992;             //   100,352  (inclusive je offsets)
    int*   bin     = iw + 105344;           // 1,700,000  (pk -> sorted src in place)
    float* asrc1   = fw + 1805344;          //   400,000  ([n][4] rows)
    float* adst1   = fw + 2205344;          //   400,000
    float* g       = fw + 2605344;          //   100,032
    __half* h1h    = (__half*)(fw + 2705376); // 6.4M halves, node-major [n][64]
    // total 5,905,376 slots = 23.6 MB

    hipMemsetAsync(bcnt, 0, NBK * sizeof(int), stream);

    k_g1bc  <<<GEMM_NB + BC_NB, 256, 0, stream>>>(x, ei, W1, as1, ad1,
                                                  h1h, asrc1, adst1, bcnt);
    k_bscan <<<1, 1024, 0, stream>>>(bcnt, bbase, bcursor);
    k_bscat <<<SCAT_NB, BS, 0, stream>>>(ei, bcursor, bin);
    k_e1agg <<<NBK, 256, 0, stream>>>(bin, bbase, bcnt, asrc1, adst1, h1h,
                                      b1, W2, g, A);
    k_e2agg <<<NBK, 256, 0, stream>>>(bin, A, bbase, bcnt, g, as2, ad2, b2, out);
}